// Round 8
// baseline (1300.729 us; speedup 1.0000x reference)
//
#include <hip/hip_runtime.h>
#include <math.h>

#define N_NODES 16384
#define N_EDGES 524288
#define D_FEAT  128
#define BATCH   4
#define NPTS    4096   // points per cloud
#define KSEL    2048   // selected per cloud
#define MSEL    (BATCH*KSEL)  // 8192

#define X16(F) F(0) F(1) F(2) F(3) F(4) F(5) F(6) F(7) \
               F(8) F(9) F(10) F(11) F(12) F(13) F(14) F(15)

// ---------------------------------------------------------------------------
// Blocks 0..3: FPS (byte-identical hot loop to the measured-1105us R2/R7
// variant — every redesign regressed: pk-asm +100us, tournament +20-60us,
// two-phase reduce +160us, float4 query +worse. Do not touch without
// counter evidence). Blocks 4..2051: in-degree histogram + inv=-1 init,
// overlapped on the otherwise-idle CUs (validated in R5: no fps perturbation).
// ---------------------------------------------------------------------------

__device__ __forceinline__ unsigned long long dpp_max_step(unsigned long long p,
                                                           unsigned int slo,
                                                           unsigned int shi)
{
    unsigned long long s = (((unsigned long long)shi) << 32) | slo;
    return (s > p) ? s : p;
}

__launch_bounds__(256, 1)
__global__ void fps_deg_kernel(const float* __restrict__ pos,
                               int* __restrict__ fp_int,
                               int* __restrict__ inv,
                               float* __restrict__ out_subx,
                               float* __restrict__ out_fp,
                               const int* __restrict__ dst,
                               int* __restrict__ deg)
{
    __shared__ float sx[NPTS];
    __shared__ float sy[NPTS];
    __shared__ float sz[NPTS];
    __shared__ int   sel[KSEL];
    __shared__ unsigned long long pwv[2][4];

    if (blockIdx.x >= BATCH) {
        int e = (blockIdx.x - BATCH) * 256 + threadIdx.x;
        if (e < N_NODES) inv[e] = -1;
        atomicAdd(&deg[dst[e]], 1);
        return;
    }

    const int b   = blockIdx.x;
    const int tid = threadIdx.x;

    const float* gp = pos + (size_t)b * NPTS * 3;
    for (int i = tid; i < NPTS; i += 256) {
        sx[i] = gp[3 * i + 0];
        sy[i] = gp[3 * i + 1];
        sz[i] = gp[3 * i + 2];
    }
    __syncthreads();

#define DECL(J) float x##J, y##J, z##J, d##J;
    X16(DECL)
#undef DECL
#define LOAD(J) { int li = (J)*256 + tid; x##J = sx[li]; y##J = sy[li]; z##J = sz[li]; d##J = 1e10f; }
    X16(LOAD)
#undef LOAD

    int cur = 0;
    for (int t = 0; t < KSEL; ++t) {
        if (tid == 0) sel[t] = cur;
        float qx = sx[cur];
        float qy = sy[cur];
        float qz = sz[cur];

        float bv = -1.0f;
        int   bi = 0x7fffffff;
        // exact reference arithmetic: (dx*dx + dy*dy) + dz*dz, no fma; fminf;
        // strict > keeps smallest index on ties (j ascending = idx ascending)
#define UPD(J) { \
        float dx = __fsub_rn(x##J, qx); \
        float dy = __fsub_rn(y##J, qy); \
        float dz = __fsub_rn(z##J, qz); \
        float dd = __fadd_rn(__fadd_rn(__fmul_rn(dx, dx), __fmul_rn(dy, dy)), \
                             __fmul_rn(dz, dz)); \
        d##J = fminf(d##J, dd); \
        if (d##J > bv) { bv = d##J; bi = (J)*256 + tid; } }
        X16(UPD)
#undef UPD

        // pack: nonneg float bits are order-preserving as unsigned;
        // tie -> larger ~idx -> smaller idx (matches argmax first-occurrence)
        unsigned long long p =
            (((unsigned long long)__float_as_uint(bv)) << 32) |
            (unsigned int)(~bi);

        // DPP wave-64 max reduce into lane 63
        {
            unsigned int lo, hi, slo, shi;
#define DSTEP(CTRL) \
            lo = (unsigned int)p; hi = (unsigned int)(p >> 32); \
            slo = __builtin_amdgcn_update_dpp(0, (int)lo, CTRL, 0xf, 0xf, true); \
            shi = __builtin_amdgcn_update_dpp(0, (int)hi, CTRL, 0xf, 0xf, true); \
            p = dpp_max_step(p, slo, shi);
            DSTEP(0x111)  // row_shr:1
            DSTEP(0x112)  // row_shr:2
            DSTEP(0x114)  // row_shr:4
            DSTEP(0x118)  // row_shr:8
            DSTEP(0x142)  // row_bcast:15
            DSTEP(0x143)  // row_bcast:31
#undef DSTEP
        }

        int par = t & 1;
        if ((tid & 63) == 63) pwv[par][tid >> 6] = p;
        __syncthreads();

        unsigned long long c0 = pwv[par][0];
        unsigned long long c1 = pwv[par][1];
        unsigned long long c2 = pwv[par][2];
        unsigned long long c3 = pwv[par][3];
        unsigned long long m01 = (c0 > c1) ? c0 : c1;
        unsigned long long m23 = (c2 > c3) ? c2 : c3;
        unsigned long long mm  = (m01 > m23) ? m01 : m23;
        cur = (int)(~(unsigned int)(mm & 0xffffffffULL));
    }
    __syncthreads();

    // epilogue: write selections in parallel, coalesced
    for (int t = tid; t < KSEL; t += 256) {
        int c = sel[t];
        int g = b * NPTS + c;
        int m = b * KSEL + t;
        fp_int[m] = g;
        inv[g] = m;
        out_fp[m] = (float)g;
        out_subx[m * 3 + 0] = sx[c];
        out_subx[m * 3 + 1] = sy[c];
        out_subx[m * 3 + 2] = sz[c];
    }
}

// ---------------- exclusive scan over deg -> row_ptr (+ cursor copy) ------
__global__ void scan_kernel(const int* __restrict__ deg, int* __restrict__ row_ptr,
                            int* __restrict__ row_ptr2)
{
    __shared__ int part[1024];
    int tid = threadIdx.x;
    int base = tid * 16;
    int local[16];
    int s = 0;
#pragma unroll
    for (int j = 0; j < 16; ++j) { local[j] = s; s += deg[base + j]; }
    part[tid] = s;
    __syncthreads();
    for (int off = 1; off < 1024; off <<= 1) {
        int v = part[tid];
        int add = (tid >= off) ? part[tid - off] : 0;
        __syncthreads();
        part[tid] = v + add;
        __syncthreads();
    }
    int prefix = (tid == 0) ? 0 : part[tid - 1];
#pragma unroll
    for (int j = 0; j < 16; ++j) {
        int v = prefix + local[j];
        row_ptr[base + j]  = v;
        row_ptr2[base + j] = v;   // consumed (destroyed) by scatter as cursor
    }
    if (tid == 1023) row_ptr[N_NODES] = part[1023];
}

// ---------------- CSR scatter (row_ptr2 doubles as cursor) ----------------
__global__ void scatter_kernel(const int* __restrict__ src, const int* __restrict__ dst,
                               int* __restrict__ row_ptr2, int* __restrict__ col)
{
    int e = blockIdx.x * blockDim.x + threadIdx.x;
    if (e < N_EDGES) {
        int r = atomicAdd(&row_ptr2[dst[e]], 1);  // returns absolute slot
        col[r] = src[e];
    }
}

// ---------------- fused agg (blocks 0..2047) + edge (blocks 2048..4095) ---
__global__ void agg_edge_kernel(const float* __restrict__ feat,
                                const int* __restrict__ fp_int,
                                const int* __restrict__ row_ptr,
                                const int* __restrict__ col,
                                const int* __restrict__ deg,
                                float* __restrict__ out_subfeat,
                                const int* __restrict__ src,
                                const int* __restrict__ dst,
                                const int* __restrict__ inv,
                                const float* __restrict__ subx,
                                float* __restrict__ outd,
                                float* __restrict__ outw,
                                float* __restrict__ outm)
{
    if (blockIdx.x < 2048) {
        // mean aggregation: one wave per sampled node, lane = 2 feature cols
        int wid  = (blockIdx.x * blockDim.x + threadIdx.x) >> 6;
        int lane = threadIdx.x & 63;
        int v  = fp_int[wid];
        int s0 = row_ptr[v];
        int s1 = row_ptr[v + 1];
        float a0 = 0.0f, a1 = 0.0f;
        for (int e = s0; e < s1; ++e) {
            int s = col[e];
            const float2* f2 = (const float2*)(feat + (size_t)s * D_FEAT);
            float2 vv = f2[lane];
            a0 += vv.x;
            a1 += vv.y;
        }
        float dv = fmaxf((float)deg[v], 1.0f);
        float* o = out_subfeat + (size_t)wid * D_FEAT + lane * 2;
        o[0] = a0 / dv;
        o[1] = a1 / dv;
    } else {
        int e = (blockIdx.x - 2048) * blockDim.x + threadIdx.x;
        int ls = inv[src[e]];
        int ld = inv[dst[e]];
        bool mk = (ls >= 0) && (ld >= 0);
        float dx = 0.0f, dy = 0.0f, dz = 0.0f;
        if (mk) {
            dx = __fsub_rn(subx[ld * 3 + 0], subx[ls * 3 + 0]);
            dy = __fsub_rn(subx[ld * 3 + 1], subx[ls * 3 + 1]);
            dz = __fsub_rn(subx[ld * 3 + 2], subx[ls * 3 + 2]);
        }
        float w = sqrtf(__fadd_rn(__fadd_rn(__fmul_rn(dx, dx), __fmul_rn(dy, dy)),
                                  __fmul_rn(dz, dz)));
        outd[e * 3 + 0] = dx;
        outd[e * 3 + 1] = dy;
        outd[e * 3 + 2] = dz;
        outw[e] = w;
        outm[e] = mk ? 1.0f : 0.0f;
    }
}

// ---------------- launch ---------------------------------------------------
extern "C" void kernel_launch(void* const* d_in, const int* in_sizes, int n_in,
                              void* d_out, int out_size, void* d_ws, size_t ws_size,
                              hipStream_t stream)
{
    const float* pos  = (const float*)d_in[0];   // [16384,3]
    const float* feat = (const float*)d_in[1];   // [16384,128]
    const int*   src  = (const int*)d_in[2];     // [524288]
    const int*   dst  = (const int*)d_in[3];     // [524288]

    float* out = (float*)d_out;
    float* out_subx    = out;                                 // [8192,3]
    float* out_subfeat = out_subx + (size_t)MSEL * 3;         // [8192,128]
    float* out_d       = out_subfeat + (size_t)MSEL * D_FEAT; // [524288,3]
    float* out_w       = out_d + (size_t)N_EDGES * 3;         // [524288]
    float* out_m       = out_w + (size_t)N_EDGES;             // [524288]
    float* out_fp      = out_m + (size_t)N_EDGES;             // [8192]

    int* fp_int   = (int*)d_ws;               // 8192
    int* inv      = fp_int + MSEL;            // 16384
    int* deg      = inv + N_NODES;            // 16384
    int* row_ptr  = deg + N_NODES;            // 16385
    int* row_ptr2 = row_ptr + (N_NODES + 1);  // 16385
    int* col      = row_ptr2 + (N_NODES + 1); // 524288

    (void)hipMemsetAsync(deg, 0, (size_t)N_NODES * 4, stream);

    // FPS on blocks 0..3; deg histogram + inv init overlapped on 4..2051
    fps_deg_kernel<<<BATCH + N_EDGES / 256, 256, 0, stream>>>(
        pos, fp_int, inv, out_subx, out_fp, dst, deg);

    scan_kernel<<<1, 1024, 0, stream>>>(deg, row_ptr, row_ptr2);
    scatter_kernel<<<N_EDGES / 256, 256, 0, stream>>>(src, dst, row_ptr2, col);

    agg_edge_kernel<<<4096, 256, 0, stream>>>(feat, fp_int, row_ptr, col, deg,
                                              out_subfeat, src, dst, inv, out_subx,
                                              out_d, out_w, out_m);
}

// Round 9
// 1260.095 us; speedup vs baseline: 1.0322x; 1.0322x over previous
//
#include <hip/hip_runtime.h>
#include <math.h>

#define N_NODES 16384
#define N_EDGES 524288
#define D_FEAT  128
#define BATCH   4
#define NPTS    4096   // points per cloud
#define KSEL    2048   // selected per cloud
#define MSEL    (BATCH*KSEL)  // 8192

#define X16(F) F(0) F(1) F(2) F(3) F(4) F(5) F(6) F(7) \
               F(8) F(9) F(10) F(11) F(12) F(13) F(14) F(15)

// ---------------------------------------------------------------------------
// FPS: byte-identical hot loop to the measured-1105us R2/R7 variant.
// Regression log (do not reintroduce without counter evidence):
//   pk-asm packed math +100us; tournament-tree argmax +20-60us; two-phase
//   f32/u32 reduce +160us; float4-interleaved query +worse; fusing deg
//   blocks into this dispatch +60us AND races on inv (R8: absmax 7.2 —
//   straggler deg block clobbers inv after the fps epilogue).
// deg/scan/scatter MUST complete before fps launches (inv ordering).
// ---------------------------------------------------------------------------

__device__ __forceinline__ unsigned long long dpp_max_step(unsigned long long p,
                                                           unsigned int slo,
                                                           unsigned int shi)
{
    unsigned long long s = (((unsigned long long)shi) << 32) | slo;
    return (s > p) ? s : p;
}

__launch_bounds__(256, 1)
__global__ void fps_kernel(const float* __restrict__ pos,
                           int* __restrict__ fp_int,
                           int* __restrict__ inv,
                           float* __restrict__ out_subx,
                           float* __restrict__ out_fp)
{
    __shared__ float sx[NPTS];
    __shared__ float sy[NPTS];
    __shared__ float sz[NPTS];
    __shared__ int   sel[KSEL];
    __shared__ unsigned long long pwv[2][4];

    const int b   = blockIdx.x;
    const int tid = threadIdx.x;

    const float* gp = pos + (size_t)b * NPTS * 3;
    for (int i = tid; i < NPTS; i += 256) {
        sx[i] = gp[3 * i + 0];
        sy[i] = gp[3 * i + 1];
        sz[i] = gp[3 * i + 2];
    }
    __syncthreads();

#define DECL(J) float x##J, y##J, z##J, d##J;
    X16(DECL)
#undef DECL
#define LOAD(J) { int li = (J)*256 + tid; x##J = sx[li]; y##J = sy[li]; z##J = sz[li]; d##J = 1e10f; }
    X16(LOAD)
#undef LOAD

    int cur = 0;
    for (int t = 0; t < KSEL; ++t) {
        if (tid == 0) sel[t] = cur;
        float qx = sx[cur];
        float qy = sy[cur];
        float qz = sz[cur];

        float bv = -1.0f;
        int   bi = 0x7fffffff;
        // exact reference arithmetic: (dx*dx + dy*dy) + dz*dz, no fma; fminf;
        // strict > keeps smallest index on ties (j ascending = idx ascending)
#define UPD(J) { \
        float dx = __fsub_rn(x##J, qx); \
        float dy = __fsub_rn(y##J, qy); \
        float dz = __fsub_rn(z##J, qz); \
        float dd = __fadd_rn(__fadd_rn(__fmul_rn(dx, dx), __fmul_rn(dy, dy)), \
                             __fmul_rn(dz, dz)); \
        d##J = fminf(d##J, dd); \
        if (d##J > bv) { bv = d##J; bi = (J)*256 + tid; } }
        X16(UPD)
#undef UPD

        // pack: nonneg float bits are order-preserving as unsigned;
        // tie -> larger ~idx -> smaller idx (matches argmax first-occurrence)
        unsigned long long p =
            (((unsigned long long)__float_as_uint(bv)) << 32) |
            (unsigned int)(~bi);

        // DPP wave-64 max reduce into lane 63
        {
            unsigned int lo, hi, slo, shi;
#define DSTEP(CTRL) \
            lo = (unsigned int)p; hi = (unsigned int)(p >> 32); \
            slo = __builtin_amdgcn_update_dpp(0, (int)lo, CTRL, 0xf, 0xf, true); \
            shi = __builtin_amdgcn_update_dpp(0, (int)hi, CTRL, 0xf, 0xf, true); \
            p = dpp_max_step(p, slo, shi);
            DSTEP(0x111)  // row_shr:1
            DSTEP(0x112)  // row_shr:2
            DSTEP(0x114)  // row_shr:4
            DSTEP(0x118)  // row_shr:8
            DSTEP(0x142)  // row_bcast:15
            DSTEP(0x143)  // row_bcast:31
#undef DSTEP
        }

        int par = t & 1;
        if ((tid & 63) == 63) pwv[par][tid >> 6] = p;
        __syncthreads();

        unsigned long long c0 = pwv[par][0];
        unsigned long long c1 = pwv[par][1];
        unsigned long long c2 = pwv[par][2];
        unsigned long long c3 = pwv[par][3];
        unsigned long long m01 = (c0 > c1) ? c0 : c1;
        unsigned long long m23 = (c2 > c3) ? c2 : c3;
        unsigned long long mm  = (m01 > m23) ? m01 : m23;
        cur = (int)(~(unsigned int)(mm & 0xffffffffULL));
    }
    __syncthreads();

    // epilogue: write selections in parallel, coalesced
    for (int t = tid; t < KSEL; t += 256) {
        int c = sel[t];
        int g = b * NPTS + c;
        int m = b * KSEL + t;
        fp_int[m] = g;
        inv[g] = m;
        out_fp[m] = (float)g;
        out_subx[m * 3 + 0] = sx[c];
        out_subx[m * 3 + 1] = sy[c];
        out_subx[m * 3 + 2] = sz[c];
    }
}

// ---------------- in-degree histogram + inv init --------------------------
// Runs (and completes) BEFORE fps: inv init here is race-free.
__global__ void deg_kernel(const int* __restrict__ dst, int* __restrict__ deg,
                           int* __restrict__ inv)
{
    int e = blockIdx.x * blockDim.x + threadIdx.x;
    if (e < N_NODES) inv[e] = -1;
    if (e < N_EDGES) atomicAdd(&deg[dst[e]], 1);
}

// ---------------- exclusive scan over deg -> row_ptr (+ cursor copy) ------
__global__ void scan_kernel(const int* __restrict__ deg, int* __restrict__ row_ptr,
                            int* __restrict__ row_ptr2)
{
    __shared__ int part[1024];
    int tid = threadIdx.x;
    int base = tid * 16;
    int local[16];
    int s = 0;
#pragma unroll
    for (int j = 0; j < 16; ++j) { local[j] = s; s += deg[base + j]; }
    part[tid] = s;
    __syncthreads();
    for (int off = 1; off < 1024; off <<= 1) {
        int v = part[tid];
        int add = (tid >= off) ? part[tid - off] : 0;
        __syncthreads();
        part[tid] = v + add;
        __syncthreads();
    }
    int prefix = (tid == 0) ? 0 : part[tid - 1];
#pragma unroll
    for (int j = 0; j < 16; ++j) {
        int v = prefix + local[j];
        row_ptr[base + j]  = v;
        row_ptr2[base + j] = v;   // consumed (destroyed) by scatter as cursor
    }
    if (tid == 1023) row_ptr[N_NODES] = part[1023];
}

// ---------------- CSR scatter (row_ptr2 doubles as cursor) ----------------
__global__ void scatter_kernel(const int* __restrict__ src, const int* __restrict__ dst,
                               int* __restrict__ row_ptr2, int* __restrict__ col)
{
    int e = blockIdx.x * blockDim.x + threadIdx.x;
    if (e < N_EDGES) {
        int r = atomicAdd(&row_ptr2[dst[e]], 1);  // returns absolute slot
        col[r] = src[e];
    }
}

// ---------------- fused agg (blocks 0..2047) + edge (blocks 2048..4095) ---
__global__ void agg_edge_kernel(const float* __restrict__ feat,
                                const int* __restrict__ fp_int,
                                const int* __restrict__ row_ptr,
                                const int* __restrict__ col,
                                const int* __restrict__ deg,
                                float* __restrict__ out_subfeat,
                                const int* __restrict__ src,
                                const int* __restrict__ dst,
                                const int* __restrict__ inv,
                                const float* __restrict__ subx,
                                float* __restrict__ outd,
                                float* __restrict__ outw,
                                float* __restrict__ outm)
{
    if (blockIdx.x < 2048) {
        // mean aggregation: one wave per sampled node, lane = 2 feature cols.
        // Neighbor loop unrolled x2 with independent accumulators (two load
        // streams in flight; association change is within tolerance, CSR
        // order is already nondeterministic).
        int wid  = (blockIdx.x * blockDim.x + threadIdx.x) >> 6;
        int lane = threadIdx.x & 63;
        int v  = fp_int[wid];
        int s0 = row_ptr[v];
        int s1 = row_ptr[v + 1];
        float a0 = 0.0f, a1 = 0.0f, b0 = 0.0f, b1 = 0.0f;
        int e = s0;
        for (; e + 1 < s1; e += 2) {
            int sA = col[e];
            int sB = col[e + 1];
            float2 vA = ((const float2*)(feat + (size_t)sA * D_FEAT))[lane];
            float2 vB = ((const float2*)(feat + (size_t)sB * D_FEAT))[lane];
            a0 += vA.x; a1 += vA.y;
            b0 += vB.x; b1 += vB.y;
        }
        if (e < s1) {
            int sA = col[e];
            float2 vA = ((const float2*)(feat + (size_t)sA * D_FEAT))[lane];
            a0 += vA.x; a1 += vA.y;
        }
        a0 += b0; a1 += b1;
        float dv = fmaxf((float)deg[v], 1.0f);
        float* o = out_subfeat + (size_t)wid * D_FEAT + lane * 2;
        o[0] = a0 / dv;
        o[1] = a1 / dv;
    } else {
        int e = (blockIdx.x - 2048) * blockDim.x + threadIdx.x;
        int ls = inv[src[e]];
        int ld = inv[dst[e]];
        bool mk = (ls >= 0) && (ld >= 0);
        float dx = 0.0f, dy = 0.0f, dz = 0.0f;
        if (mk) {
            dx = __fsub_rn(subx[ld * 3 + 0], subx[ls * 3 + 0]);
            dy = __fsub_rn(subx[ld * 3 + 1], subx[ls * 3 + 1]);
            dz = __fsub_rn(subx[ld * 3 + 2], subx[ls * 3 + 2]);
        }
        float w = sqrtf(__fadd_rn(__fadd_rn(__fmul_rn(dx, dx), __fmul_rn(dy, dy)),
                                  __fmul_rn(dz, dz)));
        outd[e * 3 + 0] = dx;
        outd[e * 3 + 1] = dy;
        outd[e * 3 + 2] = dz;
        outw[e] = w;
        outm[e] = mk ? 1.0f : 0.0f;
    }
}

// ---------------- launch ---------------------------------------------------
extern "C" void kernel_launch(void* const* d_in, const int* in_sizes, int n_in,
                              void* d_out, int out_size, void* d_ws, size_t ws_size,
                              hipStream_t stream)
{
    const float* pos  = (const float*)d_in[0];   // [16384,3]
    const float* feat = (const float*)d_in[1];   // [16384,128]
    const int*   src  = (const int*)d_in[2];     // [524288]
    const int*   dst  = (const int*)d_in[3];     // [524288]

    float* out = (float*)d_out;
    float* out_subx    = out;                                 // [8192,3]
    float* out_subfeat = out_subx + (size_t)MSEL * 3;         // [8192,128]
    float* out_d       = out_subfeat + (size_t)MSEL * D_FEAT; // [524288,3]
    float* out_w       = out_d + (size_t)N_EDGES * 3;         // [524288]
    float* out_m       = out_w + (size_t)N_EDGES;             // [524288]
    float* out_fp      = out_m + (size_t)N_EDGES;             // [8192]

    int* fp_int   = (int*)d_ws;               // 8192
    int* inv      = fp_int + MSEL;            // 16384
    int* deg      = inv + N_NODES;            // 16384
    int* row_ptr  = deg + N_NODES;            // 16385
    int* row_ptr2 = row_ptr + (N_NODES + 1);  // 16385
    int* col      = row_ptr2 + (N_NODES + 1); // 524288

    (void)hipMemsetAsync(deg, 0, (size_t)N_NODES * 4, stream);

    deg_kernel<<<N_EDGES / 256, 256, 0, stream>>>(dst, deg, inv);
    scan_kernel<<<1, 1024, 0, stream>>>(deg, row_ptr, row_ptr2);
    scatter_kernel<<<N_EDGES / 256, 256, 0, stream>>>(src, dst, row_ptr2, col);

    fps_kernel<<<BATCH, 256, 0, stream>>>(pos, fp_int, inv, out_subx, out_fp);

    agg_edge_kernel<<<4096, 256, 0, stream>>>(feat, fp_int, row_ptr, col, deg,
                                              out_subfeat, src, dst, inv, out_subx,
                                              out_d, out_w, out_m);
}